// Round 2
// baseline (1805.070 us; speedup 1.0000x reference)
//
#include <hip/hip_runtime.h>
#include <hip/hip_bf16.h>
#include <math.h>

// Shapes (fixed by reference): B=1, N=2048, C=640, H=8, Dh=80, augmented keys = 4096
constexpr float KSCALE = 0.11180339887498948f;            // 80^-0.5
constexpr float GATE_A = (float)(0.5 * (1.0 - 9.0 / 29.0)); // merge_alpha0 schedule

// ---------------------------------------------------------------------------
// GEMM (NT): out[m][n] = sum_k A[m*640+k] * B[n*640+k]
// M=2048, N=640, K=640. Tile 128x128, BK=16, 256 threads, 8x8 per thread.
// ---------------------------------------------------------------------------
__device__ __forceinline__ void gemm_body128(const float* __restrict__ A,
                                             const float* __restrict__ Bm,
                                             float* __restrict__ out,
                                             int bx, int by) {
  __shared__ float As[16][132];  // [k][row], padded stride 132
  __shared__ float Bs[16][132];
  const int tid = threadIdx.x;
  const int tx = tid & 15;       // col group
  const int ty = tid >> 4;       // row group
  const int m0 = bx * 128;
  const int n0 = by * 128;
  const int lrow = tid >> 1;       // 0..127
  const int lk = (tid & 1) * 8;    // 0 or 8
  const float* Ap = A + (m0 + lrow) * 640 + lk;
  const float* Bp = Bm + (n0 + lrow) * 640 + lk;

  float acc[8][8];
#pragma unroll
  for (int i = 0; i < 8; ++i)
#pragma unroll
    for (int j = 0; j < 8; ++j) acc[i][j] = 0.f;

  for (int k0 = 0; k0 < 640; k0 += 16) {
    const float4 a0 = *(const float4*)(Ap + k0);
    const float4 a1 = *(const float4*)(Ap + k0 + 4);
    const float4 b0 = *(const float4*)(Bp + k0);
    const float4 b1 = *(const float4*)(Bp + k0 + 4);
    __syncthreads();  // previous tile fully consumed
    As[lk + 0][lrow] = a0.x; As[lk + 1][lrow] = a0.y;
    As[lk + 2][lrow] = a0.z; As[lk + 3][lrow] = a0.w;
    As[lk + 4][lrow] = a1.x; As[lk + 5][lrow] = a1.y;
    As[lk + 6][lrow] = a1.z; As[lk + 7][lrow] = a1.w;
    Bs[lk + 0][lrow] = b0.x; Bs[lk + 1][lrow] = b0.y;
    Bs[lk + 2][lrow] = b0.z; Bs[lk + 3][lrow] = b0.w;
    Bs[lk + 4][lrow] = b1.x; Bs[lk + 5][lrow] = b1.y;
    Bs[lk + 6][lrow] = b1.z; Bs[lk + 7][lrow] = b1.w;
    __syncthreads();
#pragma unroll
    for (int kk = 0; kk < 16; ++kk) {
      const float4 ra0 = *(const float4*)&As[kk][ty * 4];
      const float4 ra1 = *(const float4*)&As[kk][ty * 4 + 64];
      const float4 rb0 = *(const float4*)&Bs[kk][tx * 4];
      const float4 rb1 = *(const float4*)&Bs[kk][tx * 4 + 64];
      const float av[8] = {ra0.x, ra0.y, ra0.z, ra0.w, ra1.x, ra1.y, ra1.z, ra1.w};
      const float bv[8] = {rb0.x, rb0.y, rb0.z, rb0.w, rb1.x, rb1.y, rb1.z, rb1.w};
#pragma unroll
      for (int i = 0; i < 8; ++i)
#pragma unroll
        for (int j = 0; j < 8; ++j) acc[i][j] += av[i] * bv[j];
    }
  }

#pragma unroll
  for (int i = 0; i < 8; ++i) {
    const int row = m0 + ((i < 4) ? (ty * 4 + i) : (64 + ty * 4 + (i - 4)));
    *(float4*)(out + row * 640 + n0 + tx * 4) =
        make_float4(acc[i][0], acc[i][1], acc[i][2], acc[i][3]);
    *(float4*)(out + row * 640 + n0 + 64 + tx * 4) =
        make_float4(acc[i][4], acc[i][5], acc[i][6], acc[i][7]);
  }
}

__global__ __launch_bounds__(256) void qkv_proj_kernel(
    const float* __restrict__ x, const float* __restrict__ Wq,
    const float* __restrict__ Wk, const float* __restrict__ Wv,
    float* __restrict__ q, float* __restrict__ k, float* __restrict__ v) {
  const float* W;
  float* o;
  if (blockIdx.z == 0) { W = Wq; o = q; }
  else if (blockIdx.z == 1) { W = Wk; o = k; }
  else { W = Wv; o = v; }
  gemm_body128(x, W, o, blockIdx.x, blockIdx.y);
}

// ---------------------------------------------------------------------------
// out_proj: 64x64 tiles (4x4 per thread) -> 320 blocks, fills all 256 CUs.
// ---------------------------------------------------------------------------
__global__ __launch_bounds__(256) void out_proj_kernel(
    const float* __restrict__ A, const float* __restrict__ Bm,
    const float* __restrict__ bias, float* __restrict__ out) {
  __shared__ float As[16][68];  // [k][row], padded stride 68
  __shared__ float Bs[16][68];
  const int tid = threadIdx.x;
  const int tx = tid & 15;
  const int ty = tid >> 4;
  const int m0 = blockIdx.x * 64;
  const int n0 = blockIdx.y * 64;
  const int lrow = tid >> 2;      // 0..63
  const int lk = (tid & 3) * 4;   // 0,4,8,12
  const float* Ap = A + (m0 + lrow) * 640 + lk;
  const float* Bp = Bm + (n0 + lrow) * 640 + lk;

  float acc[4][4];
#pragma unroll
  for (int i = 0; i < 4; ++i)
#pragma unroll
    for (int j = 0; j < 4; ++j) acc[i][j] = 0.f;

  for (int k0 = 0; k0 < 640; k0 += 16) {
    const float4 a = *(const float4*)(Ap + k0);
    const float4 b = *(const float4*)(Bp + k0);
    __syncthreads();
    As[lk + 0][lrow] = a.x; As[lk + 1][lrow] = a.y;
    As[lk + 2][lrow] = a.z; As[lk + 3][lrow] = a.w;
    Bs[lk + 0][lrow] = b.x; Bs[lk + 1][lrow] = b.y;
    Bs[lk + 2][lrow] = b.z; Bs[lk + 3][lrow] = b.w;
    __syncthreads();
#pragma unroll
    for (int kk = 0; kk < 16; ++kk) {
      const float4 ra = *(const float4*)&As[kk][ty * 4];
      const float4 rb = *(const float4*)&Bs[kk][tx * 4];
      const float av[4] = {ra.x, ra.y, ra.z, ra.w};
      const float bv[4] = {rb.x, rb.y, rb.z, rb.w};
#pragma unroll
      for (int i = 0; i < 4; ++i)
#pragma unroll
        for (int j = 0; j < 4; ++j) acc[i][j] += av[i] * bv[j];
    }
  }

  const float4 b4 = *(const float4*)(bias + n0 + tx * 4);
#pragma unroll
  for (int i = 0; i < 4; ++i) {
    const int row = m0 + ty * 4 + i;
    *(float4*)(out + row * 640 + n0 + tx * 4) =
        make_float4(acc[i][0] + b4.x, acc[i][1] + b4.y,
                    acc[i][2] + b4.z, acc[i][3] + b4.w);
  }
}

// ---------------------------------------------------------------------------
// Head-mean + L2-normalize. One wave per token row. dst[n][80].
// element (h, n, dh) at src[n*rowStride + h*headStride + dh]
// ---------------------------------------------------------------------------
__global__ __launch_bounds__(256) void feats_kernel(const float* __restrict__ src,
                                                    float* __restrict__ dst,
                                                    int rowStride, int headStride) {
  const int w = threadIdx.x >> 6;
  const int lane = threadIdx.x & 63;
  const int n = blockIdx.x * 4 + w;
  const float* base = src + (size_t)n * rowStride;
  float e0 = 0.f, e1 = 0.f;
  const int l2 = 64 + (lane & 15);  // always-valid address; value used only when lane<16
#pragma unroll
  for (int hh = 0; hh < 8; ++hh) {
    e0 += base[hh * headStride + lane];
    e1 += base[hh * headStride + l2];
  }
  e0 *= 0.125f;
  e1 *= 0.125f;
  float ss = e0 * e0 + ((lane < 16) ? e1 * e1 : 0.f);
#pragma unroll
  for (int mask = 1; mask <= 32; mask <<= 1) ss += __shfl_xor(ss, mask);
  const float inv = 1.f / fmaxf(sqrtf(ss), 1e-12f);
  dst[n * 80 + lane] = e0 * inv;
  if (lane < 16) dst[n * 80 + 64 + lane] = e1 * inv;
}

// ---------------------------------------------------------------------------
// Row-argmax of ff @ gg^T (2048x2048, Dh=80), first-max tie semantics.
// Block: 16 rows, 256 threads (16 threads per row). m-tiles of 64 in LDS.
// ---------------------------------------------------------------------------
__global__ __launch_bounds__(256) void argmax_kernel(const float* __restrict__ ff,
                                                     const float* __restrict__ gg,
                                                     int* __restrict__ idxArr,
                                                     float* __restrict__ confArr) {
  __shared__ float ffs[16][80];
  __shared__ float ggs[64][84];
  const int tid = threadIdx.x;
  const int rbase = blockIdx.x * 16;
  for (int i = tid; i < 16 * 80; i += 256)
    ffs[i / 80][i % 80] = ff[(rbase + i / 80) * 80 + (i % 80)];

  const int row = tid >> 4;  // 0..15
  const int mc = tid & 15;
  float best = -1e30f;
  int bidx = 0;

  for (int mt = 0; mt < 32; ++mt) {
    __syncthreads();
    for (int i = tid; i < 64 * 80; i += 256)
      ggs[i / 80][i % 80] = gg[(mt * 64 + i / 80) * 80 + (i % 80)];
    __syncthreads();
#pragma unroll
    for (int kk = 0; kk < 4; ++kk) {
      const int mloc = mc + kk * 16;
      float s0 = 0.f, s1 = 0.f, s2 = 0.f, s3 = 0.f;
#pragma unroll
      for (int d = 0; d < 80; d += 4) {
        const float4 f4 = *(const float4*)&ffs[row][d];
        const float4 g4 = *(const float4*)&ggs[mloc][d];
        s0 += f4.x * g4.x; s1 += f4.y * g4.y;
        s2 += f4.z * g4.z; s3 += f4.w * g4.w;
      }
      const float s = (s0 + s1) + (s2 + s3);
      if (s > best) { best = s; bidx = mt * 64 + mloc; }  // ascending m -> strict >
    }
  }
  // cross-lane reduce within the 16-lane row group; prefer larger, then lower idx
#pragma unroll
  for (int mask = 1; mask <= 8; mask <<= 1) {
    const float vb = __shfl_xor(best, mask);
    const int ib = __shfl_xor(bidx, mask);
    if (vb > best || (vb == best && ib < bidx)) { best = vb; bidx = ib; }
  }
  if (mc == 0) {
    idxArr[rbase + row] = bidx;
    const float cv = fminf(fmaxf(best, -1.f), 1.f);
    confArr[rbase + row] = (cv + 1.f) * 0.5f;
  }
}

// ---------------------------------------------------------------------------
// Flash attention over 4096 augmented keys + confidence-gated merge.
// Block: 256 threads = 32 query rows x 8 key-chunks. Grid: (64 qtiles, 8 heads).
// Q row and O accumulator in registers; K/V tiles in LDS, read as broadcasts
// (8 distinct addrs/wave, stride 84 -> banks {0,20,8,28,16,4,24,12}: disjoint).
// Tiles of 64 keys are uniformly frame (kt<32) or identity (kt>=32).
// ---------------------------------------------------------------------------
__global__ __launch_bounds__(256, 2) void attn_kernel(
    const float* __restrict__ q, const float* __restrict__ k,
    const float* __restrict__ v, const float* __restrict__ id_k,
    const float* __restrict__ id_v, const float* __restrict__ id_out,
    const int* __restrict__ idxArr, const float* __restrict__ confArr,
    float* __restrict__ om) {
  __shared__ float ks[64][84];
  __shared__ float vs[64][84];
  const int h = blockIdx.y;
  const int tid = threadIdx.x;
  const int rl = tid >> 3;  // local row 0..31
  const int ch = tid & 7;   // key chunk 0..7
  const int n = blockIdx.x * 32 + rl;

  float qr[80];
  {
    const float* qp = q + n * 640 + h * 80;
#pragma unroll
    for (int d = 0; d < 80; ++d) qr[d] = qp[d];
  }
  float o[80];
#pragma unroll
  for (int d = 0; d < 80; ++d) o[d] = 0.f;
  float m_i = -INFINITY, l_i = 0.f;

  for (int kt = 0; kt < 64; ++kt) {  // 4096 keys / 64 per tile
    __syncthreads();
    if (kt < 32) {                   // frame keys: uniform branch per tile
      const float* kb = k + (kt << 6) * 640 + h * 80;
      const float* vb = v + (kt << 6) * 640 + h * 80;
#pragma unroll
      for (int t = 0; t < 20; ++t) {
        const int i = tid + t * 256;
        const int c = i / 80;
        const int d = i - c * 80;
        ks[c][d] = kb[c * 640 + d];
        vs[c][d] = vb[c * 640 + d];
      }
    } else {                         // identity keys: gather via idx
      const int* ip = idxArr + ((kt - 32) << 6);
      const float* kb = id_k + h * 163840;
      const float* vb = id_v + h * 163840;
#pragma unroll
      for (int t = 0; t < 20; ++t) {
        const int i = tid + t * 256;
        const int c = i / 80;
        const int d = i - c * 80;
        const int j = ip[c];
        ks[c][d] = kb[j * 80 + d];
        vs[c][d] = vb[j * 80 + d];
      }
    }
    __syncthreads();
#pragma unroll 2
    for (int ii = 0; ii < 8; ++ii) {
      const int c = ch + (ii << 3);
      float s0 = 0.f, s1 = 0.f, s2 = 0.f, s3 = 0.f;
#pragma unroll
      for (int d = 0; d < 80; d += 4) {
        const float4 k4 = *(const float4*)&ks[c][d];
        s0 += qr[d] * k4.x;
        s1 += qr[d + 1] * k4.y;
        s2 += qr[d + 2] * k4.z;
        s3 += qr[d + 3] * k4.w;
      }
      const float s = ((s0 + s1) + (s2 + s3)) * KSCALE;
      if (s > m_i) {          // new running max: rescale path (rare in steady state)
        const float corr = __expf(m_i - s);  // exp(-inf)=0 on first key
        m_i = s;
        l_i = l_i * corr + 1.f;              // p = exp(s - s) = 1
#pragma unroll
        for (int d = 0; d < 80; d += 4) {
          const float4 v4 = *(const float4*)&vs[c][d];
          o[d]     = o[d]     * corr + v4.x;
          o[d + 1] = o[d + 1] * corr + v4.y;
          o[d + 2] = o[d + 2] * corr + v4.z;
          o[d + 3] = o[d + 3] * corr + v4.w;
        }
      } else {                // common path: no rescale
        const float p = __expf(s - m_i);
        l_i += p;
#pragma unroll
        for (int d = 0; d < 80; d += 4) {
          const float4 v4 = *(const float4*)&vs[c][d];
          o[d]     += p * v4.x;
          o[d + 1] += p * v4.y;
          o[d + 2] += p * v4.z;
          o[d + 3] += p * v4.w;
        }
      }
    }
  }

  // combine the 8 key-chunk partials (lane bits 0..2)
#pragma unroll
  for (int mask = 1; mask <= 4; mask <<= 1) {
    const float m_o = __shfl_xor(m_i, mask);
    const float l_o = __shfl_xor(l_i, mask);
    const float M = fmaxf(m_i, m_o);
    const float a = __expf(m_i - M);
    const float b = __expf(m_o - M);
    l_i = l_i * a + l_o * b;
    m_i = M;
#pragma unroll
    for (int d = 0; d < 80; ++d) {
      const float oo = __shfl_xor(o[d], mask);
      o[d] = o[d] * a + oo * b;
    }
  }

  const float inv_l = 1.f / l_i;
  const float g = GATE_A * confArr[n];
  const float omg = 1.f - g;
  const int j = idxArr[n];
  const float* po = id_out + (h * 2048 + j) * 80;
  float* op = om + n * 640 + h * 80;
  if (ch == 0) {
#pragma unroll
    for (int d = 0; d < 80; ++d) op[d] = o[d] * inv_l * omg + po[d] * g;
  }
}

// ---------------------------------------------------------------------------
extern "C" void kernel_launch(void* const* d_in, const int* in_sizes, int n_in,
                              void* d_out, int out_size, void* d_ws, size_t ws_size,
                              hipStream_t stream) {
  (void)in_sizes; (void)n_in; (void)out_size; (void)ws_size;
  const float* x    = (const float*)d_in[0];
  const float* Wq   = (const float*)d_in[1];
  const float* Wk   = (const float*)d_in[2];
  const float* Wv   = (const float*)d_in[3];
  const float* Wo   = (const float*)d_in[4];
  const float* bo   = (const float*)d_in[5];
  const float* id_k = (const float*)d_in[6];
  const float* id_v = (const float*)d_in[7];
  const float* id_o = (const float*)d_in[8];
  float* out = (float*)d_out;

  // workspace layout (floats): q,k,v,om [2048x640] each; ff,gg [2048x80]; conf; idx
  float* wsf  = (float*)d_ws;
  float* q    = wsf;
  float* k    = wsf + 1310720;
  float* v    = wsf + 2621440;
  float* om   = wsf + 3932160;
  float* ff   = wsf + 5242880;
  float* gg   = wsf + 5406720;
  float* conf = wsf + 5570560;
  int*   idxA = (int*)(wsf + 5572608);

  const dim3 blk(256);
  qkv_proj_kernel<<<dim3(16, 5, 3), blk, 0, stream>>>(x, Wq, Wk, Wv, q, k, v);
  feats_kernel<<<dim3(512), blk, 0, stream>>>(k, ff, 640, 80);          // f_feats from kh
  feats_kernel<<<dim3(512), blk, 0, stream>>>(id_k, gg, 80, 163840);    // id_feats
  argmax_kernel<<<dim3(128), blk, 0, stream>>>(ff, gg, idxA, conf);
  attn_kernel<<<dim3(64, 8), blk, 0, stream>>>(q, k, v, id_k, id_v, id_o, idxA, conf, om);
  out_proj_kernel<<<dim3(32, 10), blk, 0, stream>>>(om, Wo, bo, out);
}

// Round 6
// 1481.851 us; speedup vs baseline: 1.2181x; 1.2181x over previous
//
#include <hip/hip_runtime.h>
#include <hip/hip_bf16.h>
#include <math.h>

// Shapes (fixed by reference): B=1, N=2048, C=640, H=8, Dh=80, augmented keys = 4096
constexpr float KSCALE = 0.11180339887498948f;            // 80^-0.5
constexpr float GATE_A = (float)(0.5 * (1.0 - 9.0 / 29.0)); // merge_alpha0 schedule

// ---------------------------------------------------------------------------
// GEMM (NT): out[m][n] = sum_k A[m*640+k] * B[n*640+k]
// M=2048, N=640, K=640. Tile 128x128, BK=16, 256 threads, 8x8 per thread.
// ---------------------------------------------------------------------------
__device__ __forceinline__ void gemm_body128(const float* __restrict__ A,
                                             const float* __restrict__ Bm,
                                             float* __restrict__ out,
                                             int bx, int by) {
  __shared__ float As[16][132];  // [k][row], padded stride 132
  __shared__ float Bs[16][132];
  const int tid = threadIdx.x;
  const int tx = tid & 15;       // col group
  const int ty = tid >> 4;       // row group
  const int m0 = bx * 128;
  const int n0 = by * 128;
  const int lrow = tid >> 1;       // 0..127
  const int lk = (tid & 1) * 8;    // 0 or 8
  const float* Ap = A + (m0 + lrow) * 640 + lk;
  const float* Bp = Bm + (n0 + lrow) * 640 + lk;

  float acc[8][8];
#pragma unroll
  for (int i = 0; i < 8; ++i)
#pragma unroll
    for (int j = 0; j < 8; ++j) acc[i][j] = 0.f;

  for (int k0 = 0; k0 < 640; k0 += 16) {
    const float4 a0 = *(const float4*)(Ap + k0);
    const float4 a1 = *(const float4*)(Ap + k0 + 4);
    const float4 b0 = *(const float4*)(Bp + k0);
    const float4 b1 = *(const float4*)(Bp + k0 + 4);
    __syncthreads();  // previous tile fully consumed
    As[lk + 0][lrow] = a0.x; As[lk + 1][lrow] = a0.y;
    As[lk + 2][lrow] = a0.z; As[lk + 3][lrow] = a0.w;
    As[lk + 4][lrow] = a1.x; As[lk + 5][lrow] = a1.y;
    As[lk + 6][lrow] = a1.z; As[lk + 7][lrow] = a1.w;
    Bs[lk + 0][lrow] = b0.x; Bs[lk + 1][lrow] = b0.y;
    Bs[lk + 2][lrow] = b0.z; Bs[lk + 3][lrow] = b0.w;
    Bs[lk + 4][lrow] = b1.x; Bs[lk + 5][lrow] = b1.y;
    Bs[lk + 6][lrow] = b1.z; Bs[lk + 7][lrow] = b1.w;
    __syncthreads();
#pragma unroll
    for (int kk = 0; kk < 16; ++kk) {
      const float4 ra0 = *(const float4*)&As[kk][ty * 4];
      const float4 ra1 = *(const float4*)&As[kk][ty * 4 + 64];
      const float4 rb0 = *(const float4*)&Bs[kk][tx * 4];
      const float4 rb1 = *(const float4*)&Bs[kk][tx * 4 + 64];
      const float av[8] = {ra0.x, ra0.y, ra0.z, ra0.w, ra1.x, ra1.y, ra1.z, ra1.w};
      const float bv[8] = {rb0.x, rb0.y, rb0.z, rb0.w, rb1.x, rb1.y, rb1.z, rb1.w};
#pragma unroll
      for (int i = 0; i < 8; ++i)
#pragma unroll
        for (int j = 0; j < 8; ++j) acc[i][j] += av[i] * bv[j];
    }
  }

#pragma unroll
  for (int i = 0; i < 8; ++i) {
    const int row = m0 + ((i < 4) ? (ty * 4 + i) : (64 + ty * 4 + (i - 4)));
    *(float4*)(out + row * 640 + n0 + tx * 4) =
        make_float4(acc[i][0], acc[i][1], acc[i][2], acc[i][3]);
    *(float4*)(out + row * 640 + n0 + 64 + tx * 4) =
        make_float4(acc[i][4], acc[i][5], acc[i][6], acc[i][7]);
  }
}

__global__ __launch_bounds__(256) void qkv_proj_kernel(
    const float* __restrict__ x, const float* __restrict__ Wq,
    const float* __restrict__ Wk, const float* __restrict__ Wv,
    float* __restrict__ q, float* __restrict__ k, float* __restrict__ v) {
  const float* W;
  float* o;
  if (blockIdx.z == 0) { W = Wq; o = q; }
  else if (blockIdx.z == 1) { W = Wk; o = k; }
  else { W = Wv; o = v; }
  gemm_body128(x, W, o, blockIdx.x, blockIdx.y);
}

// ---------------------------------------------------------------------------
// out_proj: 64x64 tiles (4x4 per thread) -> 320 blocks, fills all 256 CUs.
// ---------------------------------------------------------------------------
__global__ __launch_bounds__(256) void out_proj_kernel(
    const float* __restrict__ A, const float* __restrict__ Bm,
    const float* __restrict__ bias, float* __restrict__ out) {
  __shared__ float As[16][68];  // [k][row], padded stride 68
  __shared__ float Bs[16][68];
  const int tid = threadIdx.x;
  const int tx = tid & 15;
  const int ty = tid >> 4;
  const int m0 = blockIdx.x * 64;
  const int n0 = blockIdx.y * 64;
  const int lrow = tid >> 2;      // 0..63
  const int lk = (tid & 3) * 4;   // 0,4,8,12
  const float* Ap = A + (m0 + lrow) * 640 + lk;
  const float* Bp = Bm + (n0 + lrow) * 640 + lk;

  float acc[4][4];
#pragma unroll
  for (int i = 0; i < 4; ++i)
#pragma unroll
    for (int j = 0; j < 4; ++j) acc[i][j] = 0.f;

  for (int k0 = 0; k0 < 640; k0 += 16) {
    const float4 a = *(const float4*)(Ap + k0);
    const float4 b = *(const float4*)(Bp + k0);
    __syncthreads();
    As[lk + 0][lrow] = a.x; As[lk + 1][lrow] = a.y;
    As[lk + 2][lrow] = a.z; As[lk + 3][lrow] = a.w;
    Bs[lk + 0][lrow] = b.x; Bs[lk + 1][lrow] = b.y;
    Bs[lk + 2][lrow] = b.z; Bs[lk + 3][lrow] = b.w;
    __syncthreads();
#pragma unroll
    for (int kk = 0; kk < 16; ++kk) {
      const float4 ra = *(const float4*)&As[kk][ty * 4];
      const float4 rb = *(const float4*)&Bs[kk][tx * 4];
      const float av[4] = {ra.x, ra.y, ra.z, ra.w};
      const float bv[4] = {rb.x, rb.y, rb.z, rb.w};
#pragma unroll
      for (int i = 0; i < 4; ++i)
#pragma unroll
        for (int j = 0; j < 4; ++j) acc[i][j] += av[i] * bv[j];
    }
  }

  const float4 b4 = *(const float4*)(bias + n0 + tx * 4);
#pragma unroll
  for (int i = 0; i < 4; ++i) {
    const int row = m0 + ty * 4 + i;
    *(float4*)(out + row * 640 + n0 + tx * 4) =
        make_float4(acc[i][0] + b4.x, acc[i][1] + b4.y,
                    acc[i][2] + b4.z, acc[i][3] + b4.w);
  }
}

// ---------------------------------------------------------------------------
// Head-mean + L2-normalize. One wave per token row. dst[n][80].
// ---------------------------------------------------------------------------
__global__ __launch_bounds__(256) void feats_kernel(const float* __restrict__ src,
                                                    float* __restrict__ dst,
                                                    int rowStride, int headStride) {
  const int w = threadIdx.x >> 6;
  const int lane = threadIdx.x & 63;
  const int n = blockIdx.x * 4 + w;
  const float* base = src + (size_t)n * rowStride;
  float e0 = 0.f, e1 = 0.f;
  const int l2 = 64 + (lane & 15);  // always-valid address; value used only when lane<16
#pragma unroll
  for (int hh = 0; hh < 8; ++hh) {
    e0 += base[hh * headStride + lane];
    e1 += base[hh * headStride + l2];
  }
  e0 *= 0.125f;
  e1 *= 0.125f;
  float ss = e0 * e0 + ((lane < 16) ? e1 * e1 : 0.f);
#pragma unroll
  for (int mask = 1; mask <= 32; mask <<= 1) ss += __shfl_xor(ss, mask);
  const float inv = 1.f / fmaxf(sqrtf(ss), 1e-12f);
  dst[n * 80 + lane] = e0 * inv;
  if (lane < 16) dst[n * 80 + 64 + lane] = e1 * inv;
}

// ---------------------------------------------------------------------------
// Row-argmax of ff @ gg^T (2048x2048, Dh=80), first-max tie semantics.
// ---------------------------------------------------------------------------
__global__ __launch_bounds__(256) void argmax_kernel(const float* __restrict__ ff,
                                                     const float* __restrict__ gg,
                                                     int* __restrict__ idxArr,
                                                     float* __restrict__ confArr) {
  __shared__ float ffs[16][80];
  __shared__ float ggs[64][84];
  const int tid = threadIdx.x;
  const int rbase = blockIdx.x * 16;
  for (int i = tid; i < 16 * 80; i += 256)
    ffs[i / 80][i % 80] = ff[(rbase + i / 80) * 80 + (i % 80)];

  const int row = tid >> 4;  // 0..15
  const int mc = tid & 15;
  float best = -1e30f;
  int bidx = 0;

  for (int mt = 0; mt < 32; ++mt) {
    __syncthreads();
    for (int i = tid; i < 64 * 80; i += 256)
      ggs[i / 80][i % 80] = gg[(mt * 64 + i / 80) * 80 + (i % 80)];
    __syncthreads();
#pragma unroll
    for (int kk = 0; kk < 4; ++kk) {
      const int mloc = mc + kk * 16;
      float s0 = 0.f, s1 = 0.f, s2 = 0.f, s3 = 0.f;
#pragma unroll
      for (int d = 0; d < 80; d += 4) {
        const float4 f4 = *(const float4*)&ffs[row][d];
        const float4 g4 = *(const float4*)&ggs[mloc][d];
        s0 += f4.x * g4.x; s1 += f4.y * g4.y;
        s2 += f4.z * g4.z; s3 += f4.w * g4.w;
      }
      const float s = (s0 + s1) + (s2 + s3);
      if (s > best) { best = s; bidx = mt * 64 + mloc; }  // ascending m -> strict >
    }
  }
#pragma unroll
  for (int mask = 1; mask <= 8; mask <<= 1) {
    const float vb = __shfl_xor(best, mask);
    const int ib = __shfl_xor(bidx, mask);
    if (vb > best || (vb == best && ib < bidx)) { best = vb; bidx = ib; }
  }
  if (mc == 0) {
    idxArr[rbase + row] = bidx;
    const float cv = fminf(fmaxf(best, -1.f), 1.f);
    confArr[rbase + row] = (cv + 1.f) * 0.5f;
  }
}

// ---------------------------------------------------------------------------
// Flash attention over 4096 augmented keys + confidence-gated merge.
// Flat grid 512; head = bid & 7 pins all 64 blocks of a head onto one XCD
// (round-robin dispatch) so the head's K/V (~2.6 MB) lives in that XCD's L2.
// Staging: float4 reg-staged, issued for tile t+1 before computing tile t
// (T14 async split) — latency hides under compute.
// Compute: 32 rows x 8 key-chunks; K/V LDS reads are 8-addr broadcasts,
// stride 84 -> bank spans {0,20,8,28,16,4,24,12}+[0,3]: conflict-free.
// __launch_bounds__(256,1): R2 profile showed VGPR_Count=128 < live set
// (~170 floats) => forced spill. min-waves=1 lets the allocator take ~220
// VGPRs (o[80]+qr[80]+rk/rv[40]) with zero spill; 2 blocks/CU still fit LDS.
// ---------------------------------------------------------------------------
__global__ __launch_bounds__(256, 1) void attn_kernel(
    const float* __restrict__ q, const float* __restrict__ k,
    const float* __restrict__ v, const float* __restrict__ id_k,
    const float* __restrict__ id_v, const float* __restrict__ id_out,
    const int* __restrict__ idxArr, const float* __restrict__ confArr,
    float* __restrict__ om) {
  __shared__ float ks[64][84];
  __shared__ float vs[64][84];
  const int bid = blockIdx.x;
  const int h = bid & 7;        // XCD-pinned head
  const int qt = bid >> 3;      // query tile 0..63
  const int tid = threadIdx.x;
  const int rl = tid >> 3;  // local row 0..31
  const int ch = tid & 7;   // key chunk 0..7
  const int n = qt * 32 + rl;

  // staging geometry: 1280 float4 per matrix, 5 per thread
  int cs[5], dfs[5];
#pragma unroll
  for (int j = 0; j < 5; ++j) {
    const int f = tid + 256 * j;
    cs[j] = f / 20;
    dfs[j] = (f - cs[j] * 20) * 4;
  }

  float qr[80];
  {
    const float* qp = q + n * 640 + h * 80;
#pragma unroll
    for (int d = 0; d < 80; ++d) qr[d] = qp[d];
  }
  float o[80];
#pragma unroll
  for (int d = 0; d < 80; ++d) o[d] = 0.f;
  float m_i = -INFINITY, l_i = 0.f;

  const float* kb_f = k + h * 80;
  const float* vb_f = v + h * 80;
  const float* kb_i = id_k + h * 163840;
  const float* vb_i = id_v + h * 163840;

  float4 rk[5], rv[5];
  // prologue: load tile 0 (frame)
#pragma unroll
  for (int j = 0; j < 5; ++j) {
    rk[j] = *(const float4*)(kb_f + cs[j] * 640 + dfs[j]);
    rv[j] = *(const float4*)(vb_f + cs[j] * 640 + dfs[j]);
  }

  for (int kt = 0; kt < 64; ++kt) {
    __syncthreads();   // previous tile's LDS fully consumed
#pragma unroll
    for (int j = 0; j < 5; ++j) {
      *(float4*)&ks[cs[j]][dfs[j]] = rk[j];
      *(float4*)&vs[cs[j]][dfs[j]] = rv[j];
    }
    __syncthreads();

    // issue next tile's loads now; vmcnt-wait lands at next iter's ds_write
    if (kt < 63) {
      const int nt = kt + 1;
      if (nt < 32) {
        const float* kb = kb_f + (nt << 6) * 640;
        const float* vb = vb_f + (nt << 6) * 640;
#pragma unroll
        for (int j = 0; j < 5; ++j) {
          rk[j] = *(const float4*)(kb + cs[j] * 640 + dfs[j]);
          rv[j] = *(const float4*)(vb + cs[j] * 640 + dfs[j]);
        }
      } else {
        const int* ip = idxArr + ((nt - 32) << 6);
#pragma unroll
        for (int j = 0; j < 5; ++j) {
          const int jj = ip[cs[j]];
          rk[j] = *(const float4*)(kb_i + jj * 80 + dfs[j]);
          rv[j] = *(const float4*)(vb_i + jj * 80 + dfs[j]);
        }
      }
    }

#pragma unroll 2
    for (int ii = 0; ii < 8; ++ii) {
      const int c = ch + (ii << 3);
      float s0 = 0.f, s1 = 0.f, s2 = 0.f, s3 = 0.f;
#pragma unroll
      for (int d = 0; d < 80; d += 4) {
        const float4 k4 = *(const float4*)&ks[c][d];
        s0 += qr[d] * k4.x;
        s1 += qr[d + 1] * k4.y;
        s2 += qr[d + 2] * k4.z;
        s3 += qr[d + 3] * k4.w;
      }
      const float s = ((s0 + s1) + (s2 + s3)) * KSCALE;
      if (s > m_i) {          // rescale path (rare in steady state)
        const float corr = __expf(m_i - s);  // exp(-inf)=0 on first key
        m_i = s;
        l_i = l_i * corr + 1.f;
#pragma unroll
        for (int d = 0; d < 80; d += 4) {
          const float4 v4 = *(const float4*)&vs[c][d];
          o[d]     = o[d]     * corr + v4.x;
          o[d + 1] = o[d + 1] * corr + v4.y;
          o[d + 2] = o[d + 2] * corr + v4.z;
          o[d + 3] = o[d + 3] * corr + v4.w;
        }
      } else {                // common path: no rescale
        const float p = __expf(s - m_i);
        l_i += p;
#pragma unroll
        for (int d = 0; d < 80; d += 4) {
          const float4 v4 = *(const float4*)&vs[c][d];
          o[d]     += p * v4.x;
          o[d + 1] += p * v4.y;
          o[d + 2] += p * v4.z;
          o[d + 3] += p * v4.w;
        }
      }
    }
  }

  // combine the 8 key-chunk partials (lane bits 0..2)
#pragma unroll
  for (int mask = 1; mask <= 4; mask <<= 1) {
    const float m_o = __shfl_xor(m_i, mask);
    const float l_o = __shfl_xor(l_i, mask);
    const float M = fmaxf(m_i, m_o);
    const float a = __expf(m_i - M);
    const float b = __expf(m_o - M);
    l_i = l_i * a + l_o * b;
    m_i = M;
#pragma unroll
    for (int d = 0; d < 80; ++d) {
      const float oo = __shfl_xor(o[d], mask);
      o[d] = o[d] * a + oo * b;
    }
  }

  const float inv_l = 1.f / l_i;
  const float g = GATE_A * confArr[n];
  const float omg = 1.f - g;
  const int j = idxArr[n];
  const float* po = id_out + (h * 2048 + j) * 80;
  float* op = om + n * 640 + h * 80;
  if (ch == 0) {
#pragma unroll
    for (int d = 0; d < 80; ++d) op[d] = o[d] * inv_l * omg + po[d] * g;
  }
}

// ---------------------------------------------------------------------------
extern "C" void kernel_launch(void* const* d_in, const int* in_sizes, int n_in,
                              void* d_out, int out_size, void* d_ws, size_t ws_size,
                              hipStream_t stream) {
  (void)in_sizes; (void)n_in; (void)out_size; (void)ws_size;
  const float* x    = (const float*)d_in[0];
  const float* Wq   = (const float*)d_in[1];
  const float* Wk   = (const float*)d_in[2];
  const float* Wv   = (const float*)d_in[3];
  const float* Wo   = (const float*)d_in[4];
  const float* bo   = (const float*)d_in[5];
  const float* id_k = (const float*)d_in[6];
  const float* id_v = (const float*)d_in[7];
  const float* id_o = (const float*)d_in[8];
  float* out = (float*)d_out;

  // workspace layout (floats): q,k,v,om [2048x640] each; ff,gg [2048x80]; conf; idx
  float* wsf  = (float*)d_ws;
  float* q    = wsf;
  float* k    = wsf + 1310720;
  float* v    = wsf + 2621440;
  float* om   = wsf + 3932160;
  float* ff   = wsf + 5242880;
  float* gg   = wsf + 5406720;
  float* conf = wsf + 5570560;
  int*   idxA = (int*)(wsf + 5572608);

  const dim3 blk(256);
  qkv_proj_kernel<<<dim3(16, 5, 3), blk, 0, stream>>>(x, Wq, Wk, Wv, q, k, v);
  feats_kernel<<<dim3(512), blk, 0, stream>>>(k, ff, 640, 80);          // f_feats from kh
  feats_kernel<<<dim3(512), blk, 0, stream>>>(id_k, gg, 80, 163840);    // id_feats
  argmax_kernel<<<dim3(128), blk, 0, stream>>>(ff, gg, idxA, conf);
  attn_kernel<<<dim3(512), blk, 0, stream>>>(q, k, v, id_k, id_v, id_o, idxA, conf, om);
  out_proj_kernel<<<dim3(32, 10), blk, 0, stream>>>(om, Wo, bo, out);
}

// Round 7
// 575.605 us; speedup vs baseline: 3.1360x; 2.5744x over previous
//
#include <hip/hip_runtime.h>
#include <hip/hip_bf16.h>
#include <math.h>

// Shapes (fixed by reference): B=1, N=2048, C=640, H=8, Dh=80, augmented keys = 4096
constexpr float KSCALE = 0.11180339887498948f;            // 80^-0.5
constexpr float GATE_A = (float)(0.5 * (1.0 - 9.0 / 29.0)); // merge_alpha0 schedule

typedef __attribute__((ext_vector_type(8))) short bf16x8;
typedef __attribute__((ext_vector_type(4))) float f32x4;
#define MFMA16(a, b, c) __builtin_amdgcn_mfma_f32_16x16x32_bf16(a, b, c, 0, 0, 0)

union BF8 { bf16x8 v; unsigned short s[8]; };

__device__ __forceinline__ unsigned short bf_hi(float f) {
  union { float f; unsigned u; } c{f};
  return (unsigned short)((c.u + 0x7FFFu + ((c.u >> 16) & 1u)) >> 16);  // RNE
}
__device__ __forceinline__ float bf_f(unsigned short h) {
  union { unsigned u; float f; } c{((unsigned)h) << 16};
  return c.f;
}

// ---------------------------------------------------------------------------
// GEMM (NT): out[m][n] = sum_k A[m*640+k] * B[n*640+k]
// M=2048, N=640, K=640. Tile 128x128, BK=16, 256 threads, 8x8 per thread.
// ---------------------------------------------------------------------------
__device__ __forceinline__ void gemm_body128(const float* __restrict__ A,
                                             const float* __restrict__ Bm,
                                             float* __restrict__ out,
                                             int bx, int by) {
  __shared__ float As[16][132];  // [k][row], padded stride 132
  __shared__ float Bs[16][132];
  const int tid = threadIdx.x;
  const int tx = tid & 15;       // col group
  const int ty = tid >> 4;       // row group
  const int m0 = bx * 128;
  const int n0 = by * 128;
  const int lrow = tid >> 1;       // 0..127
  const int lk = (tid & 1) * 8;    // 0 or 8
  const float* Ap = A + (m0 + lrow) * 640 + lk;
  const float* Bp = Bm + (n0 + lrow) * 640 + lk;

  float acc[8][8];
#pragma unroll
  for (int i = 0; i < 8; ++i)
#pragma unroll
    for (int j = 0; j < 8; ++j) acc[i][j] = 0.f;

  for (int k0 = 0; k0 < 640; k0 += 16) {
    const float4 a0 = *(const float4*)(Ap + k0);
    const float4 a1 = *(const float4*)(Ap + k0 + 4);
    const float4 b0 = *(const float4*)(Bp + k0);
    const float4 b1 = *(const float4*)(Bp + k0 + 4);
    __syncthreads();  // previous tile fully consumed
    As[lk + 0][lrow] = a0.x; As[lk + 1][lrow] = a0.y;
    As[lk + 2][lrow] = a0.z; As[lk + 3][lrow] = a0.w;
    As[lk + 4][lrow] = a1.x; As[lk + 5][lrow] = a1.y;
    As[lk + 6][lrow] = a1.z; As[lk + 7][lrow] = a1.w;
    Bs[lk + 0][lrow] = b0.x; Bs[lk + 1][lrow] = b0.y;
    Bs[lk + 2][lrow] = b0.z; Bs[lk + 3][lrow] = b0.w;
    Bs[lk + 4][lrow] = b1.x; Bs[lk + 5][lrow] = b1.y;
    Bs[lk + 6][lrow] = b1.z; Bs[lk + 7][lrow] = b1.w;
    __syncthreads();
#pragma unroll
    for (int kk = 0; kk < 16; ++kk) {
      const float4 ra0 = *(const float4*)&As[kk][ty * 4];
      const float4 ra1 = *(const float4*)&As[kk][ty * 4 + 64];
      const float4 rb0 = *(const float4*)&Bs[kk][tx * 4];
      const float4 rb1 = *(const float4*)&Bs[kk][tx * 4 + 64];
      const float av[8] = {ra0.x, ra0.y, ra0.z, ra0.w, ra1.x, ra1.y, ra1.z, ra1.w};
      const float bv[8] = {rb0.x, rb0.y, rb0.z, rb0.w, rb1.x, rb1.y, rb1.z, rb1.w};
#pragma unroll
      for (int i = 0; i < 8; ++i)
#pragma unroll
        for (int j = 0; j < 8; ++j) acc[i][j] += av[i] * bv[j];
    }
  }

#pragma unroll
  for (int i = 0; i < 8; ++i) {
    const int row = m0 + ((i < 4) ? (ty * 4 + i) : (64 + ty * 4 + (i - 4)));
    *(float4*)(out + row * 640 + n0 + tx * 4) =
        make_float4(acc[i][0], acc[i][1], acc[i][2], acc[i][3]);
    *(float4*)(out + row * 640 + n0 + 64 + tx * 4) =
        make_float4(acc[i][4], acc[i][5], acc[i][6], acc[i][7]);
  }
}

__global__ __launch_bounds__(256) void qkv_proj_kernel(
    const float* __restrict__ x, const float* __restrict__ Wq,
    const float* __restrict__ Wk, const float* __restrict__ Wv,
    float* __restrict__ q, float* __restrict__ k, float* __restrict__ v) {
  const float* W;
  float* o;
  if (blockIdx.z == 0) { W = Wq; o = q; }
  else if (blockIdx.z == 1) { W = Wk; o = k; }
  else { W = Wv; o = v; }
  gemm_body128(x, W, o, blockIdx.x, blockIdx.y);
}

// ---------------------------------------------------------------------------
// out_proj: 64x64 tiles (4x4 per thread) -> 320 blocks, fills all 256 CUs.
// ---------------------------------------------------------------------------
__global__ __launch_bounds__(256) void out_proj_kernel(
    const float* __restrict__ A, const float* __restrict__ Bm,
    const float* __restrict__ bias, float* __restrict__ out) {
  __shared__ float As[16][68];  // [k][row], padded stride 68
  __shared__ float Bs[16][68];
  const int tid = threadIdx.x;
  const int tx = tid & 15;
  const int ty = tid >> 4;
  const int m0 = blockIdx.x * 64;
  const int n0 = blockIdx.y * 64;
  const int lrow = tid >> 2;      // 0..63
  const int lk = (tid & 3) * 4;   // 0,4,8,12
  const float* Ap = A + (m0 + lrow) * 640 + lk;
  const float* Bp = Bm + (n0 + lrow) * 640 + lk;

  float acc[4][4];
#pragma unroll
  for (int i = 0; i < 4; ++i)
#pragma unroll
    for (int j = 0; j < 4; ++j) acc[i][j] = 0.f;

  for (int k0 = 0; k0 < 640; k0 += 16) {
    const float4 a = *(const float4*)(Ap + k0);
    const float4 b = *(const float4*)(Bp + k0);
    __syncthreads();
    As[lk + 0][lrow] = a.x; As[lk + 1][lrow] = a.y;
    As[lk + 2][lrow] = a.z; As[lk + 3][lrow] = a.w;
    Bs[lk + 0][lrow] = b.x; Bs[lk + 1][lrow] = b.y;
    Bs[lk + 2][lrow] = b.z; Bs[lk + 3][lrow] = b.w;
    __syncthreads();
#pragma unroll
    for (int kk = 0; kk < 16; ++kk) {
      const float4 ra = *(const float4*)&As[kk][ty * 4];
      const float4 rb = *(const float4*)&Bs[kk][tx * 4];
      const float av[4] = {ra.x, ra.y, ra.z, ra.w};
      const float bv[4] = {rb.x, rb.y, rb.z, rb.w};
#pragma unroll
      for (int i = 0; i < 4; ++i)
#pragma unroll
        for (int j = 0; j < 4; ++j) acc[i][j] += av[i] * bv[j];
    }
  }

  const float4 b4 = *(const float4*)(bias + n0 + tx * 4);
#pragma unroll
  for (int i = 0; i < 4; ++i) {
    const int row = m0 + ty * 4 + i;
    *(float4*)(out + row * 640 + n0 + tx * 4) =
        make_float4(acc[i][0] + b4.x, acc[i][1] + b4.y,
                    acc[i][2] + b4.z, acc[i][3] + b4.w);
  }
}

// ---------------------------------------------------------------------------
// Head-mean + L2-normalize. One wave per token row. dst[n][80].
// ---------------------------------------------------------------------------
__global__ __launch_bounds__(256) void feats_kernel(const float* __restrict__ src,
                                                    float* __restrict__ dst,
                                                    int rowStride, int headStride) {
  const int w = threadIdx.x >> 6;
  const int lane = threadIdx.x & 63;
  const int n = blockIdx.x * 4 + w;
  const float* base = src + (size_t)n * rowStride;
  float e0 = 0.f, e1 = 0.f;
  const int l2 = 64 + (lane & 15);  // always-valid address; value used only when lane<16
#pragma unroll
  for (int hh = 0; hh < 8; ++hh) {
    e0 += base[hh * headStride + lane];
    e1 += base[hh * headStride + l2];
  }
  e0 *= 0.125f;
  e1 *= 0.125f;
  float ss = e0 * e0 + ((lane < 16) ? e1 * e1 : 0.f);
#pragma unroll
  for (int mask = 1; mask <= 32; mask <<= 1) ss += __shfl_xor(ss, mask);
  const float inv = 1.f / fmaxf(sqrtf(ss), 1e-12f);
  dst[n * 80 + lane] = e0 * inv;
  if (lane < 16) dst[n * 80 + 64 + lane] = e1 * inv;
}

// ---------------------------------------------------------------------------
// Row-argmax of ff @ gg^T (2048x2048, Dh=80), first-max tie semantics.
// ---------------------------------------------------------------------------
__global__ __launch_bounds__(256) void argmax_kernel(const float* __restrict__ ff,
                                                     const float* __restrict__ gg,
                                                     int* __restrict__ idxArr,
                                                     float* __restrict__ confArr) {
  __shared__ float ffs[16][80];
  __shared__ float ggs[64][84];
  const int tid = threadIdx.x;
  const int rbase = blockIdx.x * 16;
  for (int i = tid; i < 16 * 80; i += 256)
    ffs[i / 80][i % 80] = ff[(rbase + i / 80) * 80 + (i % 80)];

  const int row = tid >> 4;  // 0..15
  const int mc = tid & 15;
  float best = -1e30f;
  int bidx = 0;

  for (int mt = 0; mt < 32; ++mt) {
    __syncthreads();
    for (int i = tid; i < 64 * 80; i += 256)
      ggs[i / 80][i % 80] = gg[(mt * 64 + i / 80) * 80 + (i % 80)];
    __syncthreads();
#pragma unroll
    for (int kk = 0; kk < 4; ++kk) {
      const int mloc = mc + kk * 16;
      float s0 = 0.f, s1 = 0.f, s2 = 0.f, s3 = 0.f;
#pragma unroll
      for (int d = 0; d < 80; d += 4) {
        const float4 f4 = *(const float4*)&ffs[row][d];
        const float4 g4 = *(const float4*)&ggs[mloc][d];
        s0 += f4.x * g4.x; s1 += f4.y * g4.y;
        s2 += f4.z * g4.z; s3 += f4.w * g4.w;
      }
      const float s = (s0 + s1) + (s2 + s3);
      if (s > best) { best = s; bidx = mt * 64 + mloc; }  // ascending m -> strict >
    }
  }
#pragma unroll
  for (int mask = 1; mask <= 8; mask <<= 1) {
    const float vb = __shfl_xor(best, mask);
    const int ib = __shfl_xor(bidx, mask);
    if (vb > best || (vb == best && ib < bidx)) { best = vb; bidx = ib; }
  }
  if (mc == 0) {
    idxArr[rbase + row] = bidx;
    const float cv = fminf(fmaxf(best, -1.f), 1.f);
    confArr[rbase + row] = (cv + 1.f) * 0.5f;
  }
}

// ---------------------------------------------------------------------------
// MFMA flash attention (bf16 hi/lo split ~= fp32 accuracy).
// 256 blocks: h = bid&7 (XCD-pinned), qt = bid>>3. 4 waves x 16 q-rows = 64.
// Per tile (64 keys): stage K (k-major, split) + V^T (XOR-swizzled, split);
// S = QK^T via 16x16x32 MFMA (3 d-chunks, d padded to 96 with zeros,
// 3 split terms qh*kh + qh*kl + ql*kh); online softmax on C-frags
// (row = 4*(l>>4)+reg, col = l&15); P f32 -> per-wave LDS -> A-frags;
// O += P*V via MFMA (3 terms). All accums f32.
// ---------------------------------------------------------------------------
__global__ __launch_bounds__(256, 1) void attn_kernel(
    const float* __restrict__ q, const float* __restrict__ k,
    const float* __restrict__ v, const float* __restrict__ id_k,
    const float* __restrict__ id_v, const float* __restrict__ id_out,
    const int* __restrict__ idxArr, const float* __restrict__ confArr,
    float* __restrict__ om) {
  __shared__ unsigned short KHI[64][96];   // [key][d], d 80..95 zeroed
  __shared__ unsigned short KLO[64][96];
  __shared__ unsigned short VTHI[80][64];  // [d][key ^ ((d&7)<<3)]
  __shared__ unsigned short VTLO[80][64];
  __shared__ float PLDS[4][16][68];        // per-wave P round-trip [q][key]

  const int bid = blockIdx.x;
  const int h = bid & 7;        // XCD-pinned head
  const int qt = bid >> 3;      // 0..31
  const int tid = threadIdx.x;
  const int wid = tid >> 6;
  const int l = tid & 63;
  const int x16 = l & 15;
  const int g = l >> 4;         // 0..3

  // zero d-pad of K arrays once (staging never writes d>=80)
  for (int i = tid; i < 1024; i += 256) {
    const int c = i >> 4, d = 80 + (i & 15);
    KHI[c][d] = 0; KLO[c][d] = 0;
  }

  // Q A-fragments: row = x16, d = dc*32 + g*8 + j; scaled by KSCALE, split
  bf16x8 qhi[3], qlo[3];
  {
    const int qrow = qt * 64 + wid * 16 + x16;
    const float* qp = q + qrow * 640 + h * 80;
#pragma unroll
    for (int dc = 0; dc < 3; ++dc) {
      BF8 hi, lo;
#pragma unroll
      for (int j = 0; j < 8; ++j) {
        const int d = dc * 32 + g * 8 + j;
        float xv = qp[(d < 80) ? d : 0];
        xv = (d < 80) ? xv * KSCALE : 0.f;
        const unsigned short hs = bf_hi(xv);
        hi.s[j] = hs;
        lo.s[j] = bf_hi(xv - bf_f(hs));
      }
      qhi[dc] = hi.v; qlo[dc] = lo.v;
    }
  }

  // staging geometry: 1280 float4 per matrix, 5 per thread
  int cs[5], dfs[5];
#pragma unroll
  for (int j = 0; j < 5; ++j) {
    const int f = tid + 256 * j;
    cs[j] = f / 20;
    dfs[j] = (f - cs[j] * 20) * 4;
  }

  f32x4 o[5];
#pragma unroll
  for (int dt = 0; dt < 5; ++dt) o[dt] = (f32x4){0.f, 0.f, 0.f, 0.f};
  float mrow[4] = {-INFINITY, -INFINITY, -INFINITY, -INFINITY};
  float lrow[4] = {0.f, 0.f, 0.f, 0.f};

  const float* kb_f = k + h * 80;
  const float* vb_f = v + h * 80;
  const float* kb_i = id_k + h * 163840;
  const float* vb_i = id_v + h * 163840;

  float4 rk[5], rv[5];
#pragma unroll
  for (int j = 0; j < 5; ++j) {  // prologue: tile 0 (frame)
    rk[j] = *(const float4*)(kb_f + cs[j] * 640 + dfs[j]);
    rv[j] = *(const float4*)(vb_f + cs[j] * 640 + dfs[j]);
  }

  for (int kt = 0; kt < 64; ++kt) {
    __syncthreads();   // previous tile's LDS fully consumed (also covers pad init)
    // convert + write K (packed u32) and V^T (scattered u16, XOR-swizzled)
#pragma unroll
    for (int j = 0; j < 5; ++j) {
      const int c = cs[j], d0 = dfs[j];
      unsigned short kh[4], kl[4];
#pragma unroll
      for (int e = 0; e < 4; ++e) {
        const float xv = (&rk[j].x)[e];
        kh[e] = bf_hi(xv);
        kl[e] = bf_hi(xv - bf_f(kh[e]));
      }
      *(unsigned int*)&KHI[c][d0]     = (unsigned)kh[0] | ((unsigned)kh[1] << 16);
      *(unsigned int*)&KHI[c][d0 + 2] = (unsigned)kh[2] | ((unsigned)kh[3] << 16);
      *(unsigned int*)&KLO[c][d0]     = (unsigned)kl[0] | ((unsigned)kl[1] << 16);
      *(unsigned int*)&KLO[c][d0 + 2] = (unsigned)kl[2] | ((unsigned)kl[3] << 16);
#pragma unroll
      for (int e = 0; e < 4; ++e) {
        const int d = d0 + e;
        const int col = c ^ ((d & 7) << 3);
        const float xv = (&rv[j].x)[e];
        const unsigned short vh = bf_hi(xv);
        VTHI[d][col] = vh;
        VTLO[d][col] = bf_hi(xv - bf_f(vh));
      }
    }
    __syncthreads();

    // prefetch next tile into registers (HBM/L2 latency hides under compute)
    if (kt < 63) {
      const int nt = kt + 1;
      if (nt < 32) {
        const float* kb = kb_f + (nt << 6) * 640;
        const float* vb = vb_f + (nt << 6) * 640;
#pragma unroll
        for (int j = 0; j < 5; ++j) {
          rk[j] = *(const float4*)(kb + cs[j] * 640 + dfs[j]);
          rv[j] = *(const float4*)(vb + cs[j] * 640 + dfs[j]);
        }
      } else {
        const int* ip = idxArr + ((nt - 32) << 6);
#pragma unroll
        for (int j = 0; j < 5; ++j) {
          const int jj = ip[cs[j]];
          rk[j] = *(const float4*)(kb_i + jj * 80 + dfs[j]);
          rv[j] = *(const float4*)(vb_i + jj * 80 + dfs[j]);
        }
      }
    }

    // ---- S = QK^T (4 key-tiles of 16) ----
    f32x4 s4[4];
#pragma unroll
    for (int t = 0; t < 4; ++t) {
      f32x4 acc = (f32x4){0.f, 0.f, 0.f, 0.f};
#pragma unroll
      for (int dc = 0; dc < 3; ++dc) {
        const bf16x8 bh = *(const bf16x8*)&KHI[t * 16 + x16][dc * 32 + g * 8];
        const bf16x8 bl = *(const bf16x8*)&KLO[t * 16 + x16][dc * 32 + g * 8];
        acc = MFMA16(qhi[dc], bh, acc);
        acc = MFMA16(qlo[dc], bh, acc);
        acc = MFMA16(qhi[dc], bl, acc);
      }
      s4[t] = acc;
    }

    // ---- online softmax (rows r: q = 4g + r; reduce over 16 lanes x16) ----
#pragma unroll
    for (int r = 0; r < 4; ++r) {
      float mt = fmaxf(fmaxf(s4[0][r], s4[1][r]), fmaxf(s4[2][r], s4[3][r]));
#pragma unroll
      for (int msk = 1; msk <= 8; msk <<= 1) mt = fmaxf(mt, __shfl_xor(mt, msk));
      const float mnew = fmaxf(mrow[r], mt);
      const float cr = __expf(mrow[r] - mnew);  // first tile: exp(-inf)=0
      const float p0 = __expf(s4[0][r] - mnew);
      const float p1 = __expf(s4[1][r] - mnew);
      const float p2 = __expf(s4[2][r] - mnew);
      const float p3 = __expf(s4[3][r] - mnew);
      s4[0][r] = p0; s4[1][r] = p1; s4[2][r] = p2; s4[3][r] = p3;
      float ps = (p0 + p1) + (p2 + p3);
#pragma unroll
      for (int msk = 1; msk <= 8; msk <<= 1) ps += __shfl_xor(ps, msk);
      lrow[r] = lrow[r] * cr + ps;
      mrow[r] = mnew;
#pragma unroll
      for (int dt = 0; dt < 5; ++dt) o[dt][r] *= cr;
    }

    // ---- P: C-layout -> per-wave LDS -> A-fragments (split) ----
#pragma unroll
    for (int t = 0; t < 4; ++t)
#pragma unroll
      for (int r = 0; r < 4; ++r)
        PLDS[wid][g * 4 + r][x16 + t * 16] = s4[t][r];

    bf16x8 pahi[2], palo[2];
#pragma unroll
    for (int kc = 0; kc < 2; ++kc) {
      const float* pr = &PLDS[wid][x16][kc * 32 + g * 8];
      BF8 hi, lo;
#pragma unroll
      for (int j = 0; j < 8; ++j) {
        const float pv = pr[j];
        const unsigned short hs = bf_hi(pv);
        hi.s[j] = hs;
        lo.s[j] = bf_hi(pv - bf_f(hs));
      }
      pahi[kc] = hi.v; palo[kc] = lo.v;
    }

    // ---- O += P * V (5 d-tiles of 16) ----
#pragma unroll
    for (int dt = 0; dt < 5; ++dt) {
      f32x4 acc = o[dt];
      const int d = dt * 16 + x16;
      const int sw = (d & 7) << 3;
#pragma unroll
      for (int kc = 0; kc < 2; ++kc) {
        const int kb = (kc * 32 + g * 8) ^ sw;
        const bf16x8 vh = *(const bf16x8*)&VTHI[d][kb];
        const bf16x8 vl = *(const bf16x8*)&VTLO[d][kb];
        acc = MFMA16(pahi[kc], vh, acc);
        acc = MFMA16(palo[kc], vh, acc);
        acc = MFMA16(pahi[kc], vl, acc);
      }
      o[dt] = acc;
    }
  }

  // ---- epilogue: normalize + confidence-gated merge ----
  const int nb = qt * 64 + wid * 16;
#pragma unroll
  for (int r = 0; r < 4; ++r) {
    const int n = nb + g * 4 + r;
    const float gt = GATE_A * confArr[n];
    const float sc = (1.f - gt) / lrow[r];
    const int jj = idxArr[n];
    const float* po = id_out + (h * 2048 + jj) * 80;
    float* op = om + n * 640 + h * 80;
#pragma unroll
    for (int dt = 0; dt < 5; ++dt) {
      const int d = dt * 16 + x16;
      op[d] = o[dt][r] * sc + po[d] * gt;
    }
  }
}

// ---------------------------------------------------------------------------
extern "C" void kernel_launch(void* const* d_in, const int* in_sizes, int n_in,
                              void* d_out, int out_size, void* d_ws, size_t ws_size,
                              hipStream_t stream) {
  (void)in_sizes; (void)n_in; (void)out_size; (void)ws_size;
  const float* x    = (const float*)d_in[0];
  const float* Wq   = (const float*)d_in[1];
  const float* Wk   = (const float*)d_in[2];
  const float* Wv   = (const float*)d_in[3];
  const float* Wo   = (const float*)d_in[4];
  const float* bo   = (const float*)d_in[5];
  const float* id_k = (const float*)d_in[6];
  const float* id_v = (const float*)d_in[7];
  const float* id_o = (const float*)d_in[8];
  float* out = (float*)d_out;

  // workspace layout (floats): q,k,v,om [2048x640] each; ff,gg [2048x80]; conf; idx
  float* wsf  = (float*)d_ws;
  float* q    = wsf;
  float* k    = wsf + 1310720;
  float* v    = wsf + 2621440;
  float* om   = wsf + 3932160;
  float* ff   = wsf + 5242880;
  float* gg   = wsf + 5406720;
  float* conf = wsf + 5570560;
  int*   idxA = (int*)(wsf + 5572608);

  const dim3 blk(256);
  qkv_proj_kernel<<<dim3(16, 5, 3), blk, 0, stream>>>(x, Wq, Wk, Wv, q, k, v);
  feats_kernel<<<dim3(512), blk, 0, stream>>>(k, ff, 640, 80);          // f_feats from kh
  feats_kernel<<<dim3(512), blk, 0, stream>>>(id_k, gg, 80, 163840);    // id_feats
  argmax_kernel<<<dim3(128), blk, 0, stream>>>(ff, gg, idxA, conf);
  attn_kernel<<<dim3(256), blk, 0, stream>>>(q, k, v, id_k, id_v, id_o, idxA, conf, om);
  out_proj_kernel<<<dim3(32, 10), blk, 0, stream>>>(om, Wo, bo, out);
}

// Round 8
// 364.363 us; speedup vs baseline: 4.9540x; 1.5798x over previous
//
#include <hip/hip_runtime.h>
#include <hip/hip_bf16.h>
#include <math.h>

// Shapes: B=1, N=2048, C=640, H=8, Dh=80, augmented keys = 4096
constexpr float KSCALE = 0.11180339887498948f;            // 80^-0.5
constexpr float GATE_A = (float)(0.5 * (1.0 - 9.0 / 29.0)); // merge_alpha0 schedule

typedef __attribute__((ext_vector_type(8))) short bf16x8;
typedef __attribute__((ext_vector_type(8))) unsigned short u16x8;
typedef __attribute__((ext_vector_type(4))) float f32x4;
#define MFMA16(a, b, c) __builtin_amdgcn_mfma_f32_16x16x32_bf16(a, b, c, 0, 0, 0)

union BF8 { bf16x8 v; unsigned short s[8]; };
union U8X { u16x8 v; unsigned short s[8]; };

__device__ __forceinline__ unsigned short bf_hi(float f) {
  union { float f; unsigned u; } c{f};
  return (unsigned short)((c.u + 0x7FFFu + ((c.u >> 16) & 1u)) >> 16);  // RNE
}
__device__ __forceinline__ float bf_f(unsigned short h) {
  union { unsigned u; float f; } c{((unsigned)h) << 16};
  return c.f;
}

// ---------------------------------------------------------------------------
// GEMM (NT): out[m][n] = sum_k A[m*640+k] * B[n*640+k]
// ---------------------------------------------------------------------------
__device__ __forceinline__ void gemm_body128(const float* __restrict__ A,
                                             const float* __restrict__ Bm,
                                             float* __restrict__ out,
                                             int bx, int by) {
  __shared__ float As[16][132];
  __shared__ float Bs[16][132];
  const int tid = threadIdx.x;
  const int tx = tid & 15;
  const int ty = tid >> 4;
  const int m0 = bx * 128;
  const int n0 = by * 128;
  const int lrow = tid >> 1;
  const int lk = (tid & 1) * 8;
  const float* Ap = A + (m0 + lrow) * 640 + lk;
  const float* Bp = Bm + (n0 + lrow) * 640 + lk;

  float acc[8][8];
#pragma unroll
  for (int i = 0; i < 8; ++i)
#pragma unroll
    for (int j = 0; j < 8; ++j) acc[i][j] = 0.f;

  for (int k0 = 0; k0 < 640; k0 += 16) {
    const float4 a0 = *(const float4*)(Ap + k0);
    const float4 a1 = *(const float4*)(Ap + k0 + 4);
    const float4 b0 = *(const float4*)(Bp + k0);
    const float4 b1 = *(const float4*)(Bp + k0 + 4);
    __syncthreads();
    As[lk + 0][lrow] = a0.x; As[lk + 1][lrow] = a0.y;
    As[lk + 2][lrow] = a0.z; As[lk + 3][lrow] = a0.w;
    As[lk + 4][lrow] = a1.x; As[lk + 5][lrow] = a1.y;
    As[lk + 6][lrow] = a1.z; As[lk + 7][lrow] = a1.w;
    Bs[lk + 0][lrow] = b0.x; Bs[lk + 1][lrow] = b0.y;
    Bs[lk + 2][lrow] = b0.z; Bs[lk + 3][lrow] = b0.w;
    Bs[lk + 4][lrow] = b1.x; Bs[lk + 5][lrow] = b1.y;
    Bs[lk + 6][lrow] = b1.z; Bs[lk + 7][lrow] = b1.w;
    __syncthreads();
#pragma unroll
    for (int kk = 0; kk < 16; ++kk) {
      const float4 ra0 = *(const float4*)&As[kk][ty * 4];
      const float4 ra1 = *(const float4*)&As[kk][ty * 4 + 64];
      const float4 rb0 = *(const float4*)&Bs[kk][tx * 4];
      const float4 rb1 = *(const float4*)&Bs[kk][tx * 4 + 64];
      const float av[8] = {ra0.x, ra0.y, ra0.z, ra0.w, ra1.x, ra1.y, ra1.z, ra1.w};
      const float bv[8] = {rb0.x, rb0.y, rb0.z, rb0.w, rb1.x, rb1.y, rb1.z, rb1.w};
#pragma unroll
      for (int i = 0; i < 8; ++i)
#pragma unroll
        for (int j = 0; j < 8; ++j) acc[i][j] += av[i] * bv[j];
    }
  }

#pragma unroll
  for (int i = 0; i < 8; ++i) {
    const int row = m0 + ((i < 4) ? (ty * 4 + i) : (64 + ty * 4 + (i - 4)));
    *(float4*)(out + row * 640 + n0 + tx * 4) =
        make_float4(acc[i][0], acc[i][1], acc[i][2], acc[i][3]);
    *(float4*)(out + row * 640 + n0 + 64 + tx * 4) =
        make_float4(acc[i][4], acc[i][5], acc[i][6], acc[i][7]);
  }
}

__global__ __launch_bounds__(256) void qkv_proj_kernel(
    const float* __restrict__ x, const float* __restrict__ Wq,
    const float* __restrict__ Wk, const float* __restrict__ Wv,
    float* __restrict__ q, float* __restrict__ k, float* __restrict__ v) {
  const float* W;
  float* o;
  if (blockIdx.z == 0) { W = Wq; o = q; }
  else if (blockIdx.z == 1) { W = Wk; o = k; }
  else { W = Wv; o = v; }
  gemm_body128(x, W, o, blockIdx.x, blockIdx.y);
}

__global__ __launch_bounds__(256) void out_proj_kernel(
    const float* __restrict__ A, const float* __restrict__ Bm,
    const float* __restrict__ bias, float* __restrict__ out) {
  __shared__ float As[16][68];
  __shared__ float Bs[16][68];
  const int tid = threadIdx.x;
  const int tx = tid & 15;
  const int ty = tid >> 4;
  const int m0 = blockIdx.x * 64;
  const int n0 = blockIdx.y * 64;
  const int lrow = tid >> 2;
  const int lk = (tid & 3) * 4;
  const float* Ap = A + (m0 + lrow) * 640 + lk;
  const float* Bp = Bm + (n0 + lrow) * 640 + lk;

  float acc[4][4];
#pragma unroll
  for (int i = 0; i < 4; ++i)
#pragma unroll
    for (int j = 0; j < 4; ++j) acc[i][j] = 0.f;

  for (int k0 = 0; k0 < 640; k0 += 16) {
    const float4 a = *(const float4*)(Ap + k0);
    const float4 b = *(const float4*)(Bp + k0);
    __syncthreads();
    As[lk + 0][lrow] = a.x; As[lk + 1][lrow] = a.y;
    As[lk + 2][lrow] = a.z; As[lk + 3][lrow] = a.w;
    Bs[lk + 0][lrow] = b.x; Bs[lk + 1][lrow] = b.y;
    Bs[lk + 2][lrow] = b.z; Bs[lk + 3][lrow] = b.w;
    __syncthreads();
#pragma unroll
    for (int kk = 0; kk < 16; ++kk) {
      const float4 ra = *(const float4*)&As[kk][ty * 4];
      const float4 rb = *(const float4*)&Bs[kk][tx * 4];
      const float av[4] = {ra.x, ra.y, ra.z, ra.w};
      const float bv[4] = {rb.x, rb.y, rb.z, rb.w};
#pragma unroll
      for (int i = 0; i < 4; ++i)
#pragma unroll
        for (int j = 0; j < 4; ++j) acc[i][j] += av[i] * bv[j];
    }
  }

  const float4 b4 = *(const float4*)(bias + n0 + tx * 4);
#pragma unroll
  for (int i = 0; i < 4; ++i) {
    const int row = m0 + ty * 4 + i;
    *(float4*)(out + row * 640 + n0 + tx * 4) =
        make_float4(acc[i][0] + b4.x, acc[i][1] + b4.y,
                    acc[i][2] + b4.z, acc[i][3] + b4.w);
  }
}

// ---------------------------------------------------------------------------
// Head-mean + L2-normalize -> bf16 hi/lo interleaved [n][160] (cols 0..79 hi,
// 80..159 lo). One wave per token row.
// ---------------------------------------------------------------------------
__global__ __launch_bounds__(256) void feats_kernel(const float* __restrict__ src,
                                                    unsigned short* __restrict__ dst,
                                                    int rowStride, int headStride) {
  const int w = threadIdx.x >> 6;
  const int lane = threadIdx.x & 63;
  const int n = blockIdx.x * 4 + w;
  const float* base = src + (size_t)n * rowStride;
  float e0 = 0.f, e1 = 0.f;
  const int l2 = 64 + (lane & 15);
#pragma unroll
  for (int hh = 0; hh < 8; ++hh) {
    e0 += base[hh * headStride + lane];
    e1 += base[hh * headStride + l2];
  }
  e0 *= 0.125f;
  e1 *= 0.125f;
  float ss = e0 * e0 + ((lane < 16) ? e1 * e1 : 0.f);
#pragma unroll
  for (int mask = 1; mask <= 32; mask <<= 1) ss += __shfl_xor(ss, mask);
  const float inv = 1.f / fmaxf(sqrtf(ss), 1e-12f);
  const float f0 = e0 * inv;
  const unsigned short h0 = bf_hi(f0);
  dst[n * 160 + lane] = h0;
  dst[n * 160 + 80 + lane] = bf_hi(f0 - bf_f(h0));
  if (lane < 16) {
    const float f1 = e1 * inv;
    const unsigned short h1 = bf_hi(f1);
    dst[n * 160 + 64 + lane] = h1;
    dst[n * 160 + 144 + lane] = bf_hi(f1 - bf_f(h1));
  }
}

// ---------------------------------------------------------------------------
// MFMA row-argmax of ff @ gg^T (bf16 hi/lo split, sim err ~1e-7).
// 32 blocks x 4 waves x 16 f-rows. C[f][m]: A = FF (regs), B = GG^T (LDS).
// First-max semantics: within-lane m ascending + strict >; cross-lane lower idx.
// ---------------------------------------------------------------------------
__global__ __launch_bounds__(256, 1) void argmax_kernel(
    const unsigned short* __restrict__ ff, const unsigned short* __restrict__ gg,
    int* __restrict__ idxArr, float* __restrict__ confArr) {
  __shared__ unsigned short GS[64][184];  // hi cols 0..79, lo 88..167 (2-way-free banks)
  const int tid = threadIdx.x;
  const int wid = tid >> 6;
  const int l = tid & 63;
  const int x16 = l & 15;
  const int g = l >> 4;
  const int frow = blockIdx.x * 64 + wid * 16 + x16;

  const bf16x8 z8 = {0, 0, 0, 0, 0, 0, 0, 0};
  bf16x8 fh[3], fl[3];
#pragma unroll
  for (int dc = 0; dc < 3; ++dc) {
    const int d0 = dc * 32 + g * 8;
    if (d0 < 80) {
      fh[dc] = *(const bf16x8*)(ff + frow * 160 + d0);
      fl[dc] = *(const bf16x8*)(ff + frow * 160 + 80 + d0);
    } else {
      fh[dc] = z8; fl[dc] = z8;
    }
  }

  int gk[5], gc[5], goff[5];
#pragma unroll
  for (int j = 0; j < 5; ++j) {
    const int e = tid + 256 * j;
    gk[j] = e / 20;
    const int s8 = e % 20;
    gc[j] = s8 * 8 + (s8 >= 10 ? 8 : 0);
    goff[j] = gk[j] * 160 + s8 * 8;
  }
  u16x8 rg[5];
#pragma unroll
  for (int j = 0; j < 5; ++j) rg[j] = *(const u16x8*)(gg + goff[j]);

  float best[4] = {-1e30f, -1e30f, -1e30f, -1e30f};
  int bidx[4] = {0, 0, 0, 0};

  for (int mt = 0; mt < 32; ++mt) {
    __syncthreads();
#pragma unroll
    for (int j = 0; j < 5; ++j) *(u16x8*)&GS[gk[j]][gc[j]] = rg[j];
    __syncthreads();
    if (mt < 31) {
      const unsigned short* gp = gg + (mt + 1) * 10240;
#pragma unroll
      for (int j = 0; j < 5; ++j) rg[j] = *(const u16x8*)(gp + goff[j]);
    }
#pragma unroll
    for (int t = 0; t < 4; ++t) {
      f32x4 acc = {0.f, 0.f, 0.f, 0.f};
#pragma unroll
      for (int dc = 0; dc < 3; ++dc) {
        const int off = (dc == 2 && g >= 2) ? 0 : dc * 32 + g * 8;  // FF zeros kill garbage
        const bf16x8 bh = *(const bf16x8*)&GS[t * 16 + x16][off];
        const bf16x8 bl = *(const bf16x8*)&GS[t * 16 + x16][88 + off];
        acc = MFMA16(fh[dc], bh, acc);
        acc = MFMA16(fl[dc], bh, acc);
        acc = MFMA16(fh[dc], bl, acc);
      }
      const int mglob = mt * 64 + t * 16 + x16;
#pragma unroll
      for (int r = 0; r < 4; ++r)
        if (acc[r] > best[r]) { best[r] = acc[r]; bidx[r] = mglob; }
    }
  }

#pragma unroll
  for (int r = 0; r < 4; ++r) {
#pragma unroll
    for (int msk = 1; msk <= 8; msk <<= 1) {
      const float vb = __shfl_xor(best[r], msk);
      const int ib = __shfl_xor(bidx[r], msk);
      if (vb > best[r] || (vb == best[r] && ib < bidx[r])) { best[r] = vb; bidx[r] = ib; }
    }
    if (x16 == 0) {
      const int fo = blockIdx.x * 64 + wid * 16 + 4 * g + r;  // C row = 4g+r
      idxArr[fo] = bidx[r];
      const float cv = fminf(fmaxf(best[r], -1.f), 1.f);
      confArr[fo] = (cv + 1.f) * 0.5f;
    }
  }
}

// ---------------------------------------------------------------------------
// Augment pre-pass: build split/gathered/transposed operand arrays ONCE.
// KA[h][4096][160]: row-major keys, cols 0..79 hi / 80..159 lo.
// VTA[h][160][4096]: d-major (rows 0..79 hi, 80..159 lo), transposed via LDS.
// Rows 0..2047 = frame k/v; 2048.. = id_k/id_v gathered by idx.
// ---------------------------------------------------------------------------
__global__ __launch_bounds__(256) void augment_kernel(
    const float* __restrict__ kin, const float* __restrict__ vin,
    const float* __restrict__ id_k, const float* __restrict__ id_v,
    const int* __restrict__ idxArr,
    unsigned short* __restrict__ KA, unsigned short* __restrict__ VTA) {
  __shared__ float VS[64][85];
  const int h = blockIdx.x & 7;
  const int nt = blockIdx.x >> 3;  // 0..63
  const int n0 = nt * 64;
  const int tid = threadIdx.x;

  int cc[5], dd[5];
  float4 kv[5], vv[5];
#pragma unroll
  for (int j = 0; j < 5; ++j) {
    const int f = tid + 256 * j;
    const int c = f / 20;
    const int d0 = (f % 20) * 4;
    cc[j] = c; dd[j] = d0;
    if (n0 < 2048) {
      kv[j] = *(const float4*)(kin + (size_t)(n0 + c) * 640 + h * 80 + d0);
      vv[j] = *(const float4*)(vin + (size_t)(n0 + c) * 640 + h * 80 + d0);
    } else {
      const int jj = idxArr[n0 + c - 2048];
      kv[j] = *(const float4*)(id_k + ((size_t)h * 2048 + jj) * 80 + d0);
      vv[j] = *(const float4*)(id_v + ((size_t)h * 2048 + jj) * 80 + d0);
    }
  }

  unsigned short* kout = KA + ((size_t)h * 4096 + n0) * 160;
#pragma unroll
  for (int j = 0; j < 5; ++j) {
    unsigned short hs[4], ls[4];
#pragma unroll
    for (int e = 0; e < 4; ++e) {
      const float xv = (&kv[j].x)[e];
      hs[e] = bf_hi(xv);
      ls[e] = bf_hi(xv - bf_f(hs[e]));
    }
    unsigned int* ph = (unsigned int*)(kout + cc[j] * 160 + dd[j]);
    ph[0] = (unsigned)hs[0] | ((unsigned)hs[1] << 16);
    ph[1] = (unsigned)hs[2] | ((unsigned)hs[3] << 16);
    unsigned int* pl = (unsigned int*)(kout + cc[j] * 160 + 80 + dd[j]);
    pl[0] = (unsigned)ls[0] | ((unsigned)ls[1] << 16);
    pl[1] = (unsigned)ls[2] | ((unsigned)ls[3] << 16);
    VS[cc[j]][dd[j] + 0] = vv[j].x;
    VS[cc[j]][dd[j] + 1] = vv[j].y;
    VS[cc[j]][dd[j] + 2] = vv[j].z;
    VS[cc[j]][dd[j] + 3] = vv[j].w;
  }
  __syncthreads();

  unsigned short* vout = VTA + (size_t)h * 160 * 4096 + n0;
#pragma unroll
  for (int j = 0; j < 5; ++j) {
    const int e = tid + 256 * j;   // 0..1279 = 160 rows x 8 chunks
    const int r = e >> 3;
    const int c8 = (e & 7) * 8;
    const int d = (r >= 80) ? r - 80 : r;
    U8X w;
#pragma unroll
    for (int qq = 0; qq < 8; ++qq) {
      const float xv = VS[c8 + qq][d];
      const unsigned short hh = bf_hi(xv);
      w.s[qq] = (r >= 80) ? bf_hi(xv - bf_f(hh)) : hh;
    }
    *(u16x8*)(vout + (size_t)r * 4096 + c8) = w.v;
  }
}

// ---------------------------------------------------------------------------
// MFMA flash attention, transposed orientation (S^T = K Q^T, O^T = V^T P^T).
// 256 blocks: h = bid&7 (XCD-pinned), qt = bid>>3; 4 waves x 16 q each.
// Staging = pure u16x8 copies from pre-split KA/VTA (reg-prefetched).
// Lane (x16=q, g): softmax reduce = 2 shuffles; P via per-wave LDS [64][18].
// All LDS strides chosen 2-way-free: KS 184 u16, VTS 72 u16, PL 18 f32.
// ---------------------------------------------------------------------------
__global__ __launch_bounds__(256, 1) void attn_kernel(
    const float* __restrict__ q,
    const unsigned short* __restrict__ KA, const unsigned short* __restrict__ VTA,
    const float* __restrict__ id_out,
    const int* __restrict__ idxArr, const float* __restrict__ confArr,
    float* __restrict__ om) {
  __shared__ unsigned short KS[64][184];   // hi 0..79, lo 88..167
  __shared__ unsigned short VTS[160][72];  // rows 0..79 hi, 80..159 lo
  __shared__ float PL[4][64][18];          // per-wave P^T[key][q]

  const int bid = blockIdx.x;
  const int h = bid & 7;
  const int qt = bid >> 3;  // 0..31
  const int tid = threadIdx.x;
  const int wid = tid >> 6;
  const int l = tid & 63;
  const int x16 = l & 15;
  const int g = l >> 4;

  // Q B-frags (lane q-row = x16-mapped), scaled, split; d>=80 zeroed
  bf16x8 qhi[3], qlo[3];
  {
    const int qrow = qt * 64 + wid * 16 + x16;
    const float* qp = q + (size_t)qrow * 640 + h * 80;
#pragma unroll
    for (int dc = 0; dc < 3; ++dc) {
      BF8 hi, lo;
#pragma unroll
      for (int j = 0; j < 8; ++j) {
        const int d = dc * 32 + g * 8 + j;
        float xv = qp[(d < 80) ? d : 0];
        xv = (d < 80) ? xv * KSCALE : 0.f;
        const unsigned short hs = bf_hi(xv);
        hi.s[j] = hs;
        lo.s[j] = bf_hi(xv - bf_f(hs));
      }
      qhi[dc] = hi.v; qlo[dc] = lo.v;
    }
  }

  // staging geometry: K part 1280 u16x8 (5/thr), VT part 1280 (5/thr)
  int kky[5], klc[5], kof[5], vr[5], vc[5], vof[5];
#pragma unroll
  for (int j = 0; j < 5; ++j) {
    const int e = tid + 256 * j;
    kky[j] = e / 20;
    const int s8 = e % 20;
    klc[j] = s8 * 8 + (s8 >= 10 ? 8 : 0);
    kof[j] = kky[j] * 160 + s8 * 8;
    vr[j] = e >> 3;
    vc[j] = (e & 7) * 8;
    vof[j] = vr[j] * 4096 + vc[j];
  }

  const unsigned short* kgb = KA + (size_t)h * 4096 * 160;
  const unsigned short* vgb = VTA + (size_t)h * 160 * 4096;

  f32x4 o[5];
#pragma unroll
  for (int dt = 0; dt < 5; ++dt) o[dt] = (f32x4){0.f, 0.f, 0.f, 0.f};
  float m_i = -INFINITY, l_i = 0.f;

  u16x8 rk[5], rv[5];
#pragma unroll
  for (int j = 0; j < 5; ++j) {  // prologue: tile 0
    rk[j] = *(const u16x8*)(kgb + kof[j]);
    rv[j] = *(const u16x8*)(vgb + vof[j]);
  }

  for (int kt = 0; kt < 64; ++kt) {
    __syncthreads();
#pragma unroll
    for (int j = 0; j < 5; ++j) {
      *(u16x8*)&KS[kky[j]][klc[j]] = rk[j];
      *(u16x8*)&VTS[vr[j]][vc[j]] = rv[j];
    }
    __syncthreads();

    if (kt < 63) {
      const unsigned short* kg = kgb + (size_t)(kt + 1) * 10240;
      const unsigned short* vg = vgb + (kt + 1) * 64;
#pragma unroll
      for (int j = 0; j < 5; ++j) {
        rk[j] = *(const u16x8*)(kg + kof[j]);
        rv[j] = *(const u16x8*)(vg + vof[j]);
      }
    }

    // ---- S^T = K Q^T: lane holds S[key=16t+4g+r][q=x16] ----
    f32x4 s4[4];
#pragma unroll
    for (int t = 0; t < 4; ++t) {
      f32x4 acc = {0.f, 0.f, 0.f, 0.f};
#pragma unroll
      for (int dc = 0; dc < 3; ++dc) {
        const int off = (dc == 2 && g >= 2) ? 0 : dc * 32 + g * 8;  // Q zeros kill garbage
        const bf16x8 ah = *(const bf16x8*)&KS[t * 16 + x16][off];
        const bf16x8 al = *(const bf16x8*)&KS[t * 16 + x16][88 + off];
        acc = MFMA16(ah, qhi[dc], acc);
        acc = MFMA16(al, qhi[dc], acc);
        acc = MFMA16(ah, qlo[dc], acc);
      }
      s4[t] = acc;
    }

    // ---- online softmax: lane owns q = x16; reduce over g (masks 16,32) ----
    float mt = s4[0][0];
#pragma unroll
    for (int t = 0; t < 4; ++t)
#pragma unroll
      for (int r = 0; r < 4; ++r) mt = fmaxf(mt, s4[t][r]);
    mt = fmaxf(mt, __shfl_xor(mt, 16));
    mt = fmaxf(mt, __shfl_xor(mt, 32));
    const float mnew = fmaxf(m_i, mt);
    const float cr = __expf(m_i - mnew);  // first tile: exp(-inf)=0
    float ps = 0.f;
#pragma unroll
    for (int t = 0; t < 4; ++t)
#pragma unroll
      for (int r = 0; r < 4; ++r) {
        const float pv = __expf(s4[t][r] - mnew);
        s4[t][r] = pv;
        ps += pv;
      }
    ps += __shfl_xor(ps, 16);
    ps += __shfl_xor(ps, 32);
    l_i = l_i * cr + ps;
    m_i = mnew;
#pragma unroll
    for (int dt = 0; dt < 5; ++dt)
#pragma unroll
      for (int r = 0; r < 4; ++r) o[dt][r] *= cr;

    // ---- P^T to per-wave LDS ----
#pragma unroll
    for (int t = 0; t < 4; ++t)
#pragma unroll
      for (int r = 0; r < 4; ++r)
        PL[wid][t * 16 + 4 * g + r][x16] = s4[t][r];

    // ---- O^T += V^T P^T ----
#pragma unroll
    for (int kb2 = 0; kb2 < 2; ++kb2) {
      float pv8[8];
#pragma unroll
      for (int j = 0; j < 8; ++j) pv8[j] = PL[wid][kb2 * 32 + g * 8 + j][x16];
      BF8 ph, pl2;
#pragma unroll
      for (int j = 0; j < 8; ++j) {
        const unsigned short hs = bf_hi(pv8[j]);
        ph.s[j] = hs;
        pl2.s[j] = bf_hi(pv8[j] - bf_f(hs));
      }
      const bf16x8 phv = ph.v, plv = pl2.v;
      const int kc = kb2 * 32 + g * 8;
#pragma unroll
      for (int dt = 0; dt < 5; ++dt) {
        const bf16x8 vh = *(const bf16x8*)&VTS[dt * 16 + x16][kc];
        const bf16x8 vl = *(const bf16x8*)&VTS[80 + dt * 16 + x16][kc];
        f32x4 acc = o[dt];
        acc = MFMA16(vh, phv, acc);
        acc = MFMA16(vl, phv, acc);
        acc = MFMA16(vh, plv, acc);
        o[dt] = acc;
      }
    }
  }

  // ---- epilogue: lane q = x16; o[dt][r] at d = 16dt + 4g + r ----
  const int n = qt * 64 + wid * 16 + x16;
  const float gt = GATE_A * confArr[n];
  const float sc = (1.f - gt) / l_i;
  const int jj = idxArr[n];
  const float* po = id_out + ((size_t)h * 2048 + jj) * 80;
  float* op = om + (size_t)n * 640 + h * 80;
#pragma unroll
  for (int dt = 0; dt < 5; ++dt)
#pragma unroll
    for (int r = 0; r < 4; ++r) {
      const int d = dt * 16 + 4 * g + r;
      op[d] = o[dt][r] * sc + po[d] * gt;
    }
}

// ---------------------------------------------------------------------------
extern "C" void kernel_launch(void* const* d_in, const int* in_sizes, int n_in,
                              void* d_out, int out_size, void* d_ws, size_t ws_size,
                              hipStream_t stream) {
  (void)in_sizes; (void)n_in; (void)out_size; (void)ws_size;
  const float* x    = (const float*)d_in[0];
  const float* Wq   = (const float*)d_in[1];
  const float* Wk   = (const float*)d_in[2];
  const float* Wv   = (const float*)d_in[3];
  const float* Wo   = (const float*)d_in[4];
  const float* bo   = (const float*)d_in[5];
  const float* id_k = (const float*)d_in[6];
  const float* id_v = (const float*)d_in[7];
  const float* id_o = (const float*)d_in[8];
  float* out = (float*)d_out;

  // ws: f32 q,k,v,om (4x 1310720) | conf | idx | u16: ffI, ggI, KA, VTA (~43 MB)
  float* wsf  = (float*)d_ws;
  float* q    = wsf;
  float* k    = wsf + 1310720;
  float* v    = wsf + 2621440;
  float* om   = wsf + 3932160;
  float* conf = wsf + 5242880;
  int*   idxA = (int*)(wsf + 5244928);
  unsigned short* ub  = (unsigned short*)(wsf + 5246976);
  unsigned short* ffI = ub;                 // [2048][160]
  unsigned short* ggI = ub + 327680;        // [2048][160]
  unsigned short* KA  = ub + 655360;        // [8][4096][160]
  unsigned short* VTA = ub + 5898240;       // [8][160][4096]

  const dim3 blk(256);
  qkv_proj_kernel<<<dim3(16, 5, 3), blk, 0, stream>>>(x, Wq, Wk, Wv, q, k, v);
  feats_kernel<<<dim3(512), blk, 0, stream>>>(k, ffI, 640, 80);
  feats_kernel<<<dim3(512), blk, 0, stream>>>(id_k, ggI, 80, 163840);
  argmax_kernel<<<dim3(32), blk, 0, stream>>>(ffI, ggI, idxA, conf);
  augment_kernel<<<dim3(512), blk, 0, stream>>>(k, v, id_k, id_v, idxA, KA, VTA);
  attn_kernel<<<dim3(256), blk, 0, stream>>>(q, KA, VTA, id_o, idxA, conf, om);
  out_proj_kernel<<<dim3(32, 10), blk, 0, stream>>>(om, Wo, bo, out);
}